// Round 8
// baseline (250.789 us; speedup 1.0000x reference)
//
#include <hip/hip_runtime.h>

// Problem constants: B=1, N=16, T=2048, E=64, H=4, D=16
#define N_ 16
#define T_ 2048
#define E_ 64
#define H_ 4
#define D_ 16
#define NH_ 64            // N_*H_
#define SEXP_ 0.18033688f // 0.125 * log2(e):  exp(s/8) == exp2(s*SEXP_)

typedef __attribute__((ext_vector_type(4))) _Float16 h4;
typedef __attribute__((ext_vector_type(8))) _Float16 h8;
typedef __attribute__((ext_vector_type(2))) __fp16 g2;
typedef __attribute__((ext_vector_type(4))) float f4;

#if __has_builtin(__builtin_amdgcn_exp2f)
__device__ inline float fast_exp2(float x) { return __builtin_amdgcn_exp2f(x); }
#else
__device__ inline float fast_exp2(float x) {
    float r; asm("v_exp_f32 %0, %1" : "=v"(r) : "v"(x)); return r;
}
#endif

#if __has_builtin(__builtin_amdgcn_rcpf)
__device__ inline float fast_rcp(float x) { return __builtin_amdgcn_rcpf(x); }
#else
__device__ inline float fast_rcp(float x) {
    float r; asm("v_rcp_f32 %0, %1" : "=v"(r) : "v"(x)); return r;
}
#endif

__device__ inline h4 pack4_f16(float a, float b, float c, float d) {
    union { g2 g[2]; h4 h; } u;
    u.g[0] = __builtin_amdgcn_cvt_pkrtz(a, b);
    u.g[1] = __builtin_amdgcn_cvt_pkrtz(c, d);
    return u.h;
}

// ---------------------------------------------------------------------------
// K1: fused projections (y=0 Q pre-scaled, y=1 K, y=2 V-transposed, y=3 Wfc^T,
//     y=4 zero out-buffer — replaces hipMemsetAsync: no API calls in capture)
// ---------------------------------------------------------------------------
__global__ __launch_bounds__(256) void proj_kernel(
    const float* __restrict__ xq, const float* __restrict__ Wq, const float* __restrict__ bq,
    const float* __restrict__ xk, const float* __restrict__ Wk, const float* __restrict__ bk,
    const float* __restrict__ xv, const float* __restrict__ Wv, const float* __restrict__ bv,
    const float* __restrict__ Wfc,
    _Float16* __restrict__ Qh, _Float16* __restrict__ Kh, _Float16* __restrict__ Vt,
    _Float16* __restrict__ Wt, float* __restrict__ outz)
{
    int tid = threadIdx.x;
    int y = blockIdx.y;
    if (y == 4) {          // zero out: 2M floats = 524288 f4 = 512*256*4
        float4 zz = {0.f, 0.f, 0.f, 0.f};
        float4* o4 = reinterpret_cast<float4*>(outz);
        int tp = blockIdx.x * 256 + tid;
#pragma unroll
        for (int s = 0; s < 4; s++) o4[tp + s * 131072] = zz;
        return;
    }
    if (y == 3) {
        if (blockIdx.x < 16) {
            int k = blockIdx.x * 4 + (tid >> 6);
            int e = tid & 63;
            Wt[e * 64 + k] = (_Float16)Wfc[k * 64 + e];
        }
        return;
    }
    const float* x = (y == 0) ? xq : (y == 1) ? xk : xv;
    const float* W = (y == 0) ? Wq : (y == 1) ? Wk : Wv;
    const float* b = (y == 0) ? bq : (y == 1) ? bk : bv;
    const float sc = (y == 0) ? SEXP_ : 1.0f;

    __shared__ float Wl[D_ * D_];
    __shared__ float bl[D_];
    Wl[tid] = W[tid];
    if (tid < D_) bl[tid] = b[tid];
    __syncthreads();

    int r = blockIdx.x * 256 + tid;
    int h, t, n;
    if (y == 2) {          // t fastest: coalesced transposed stores
        t = r & (T_ - 1);
        h = (r >> 11) & (H_ - 1);
        n = r >> 13;
    } else {               // h fastest: coalesced reads
        h = r & (H_ - 1);
        t = (r >> 2) & (T_ - 1);
        n = r >> 13;
    }

    const float4* xp4 = reinterpret_cast<const float4*>(
        x + ((size_t)(n * T_ + t) * E_ + h * D_));
    float xv_[D_];
#pragma unroll
    for (int i = 0; i < 4; i++) {
        float4 v = xp4[i];
        xv_[4*i] = v.x; xv_[4*i+1] = v.y; xv_[4*i+2] = v.z; xv_[4*i+3] = v.w;
    }
    float acc[D_];
#pragma unroll
    for (int i = 0; i < D_; i++) acc[i] = bl[i];
#pragma unroll
    for (int j = 0; j < D_; j++) {
        float xj = xv_[j];
#pragma unroll
        for (int i = 0; i < D_; i++) acc[i] = fmaf(xj, Wl[j * D_ + i], acc[i]);
    }
    if (y == 2) {
        _Float16* vb = Vt + (size_t)(n * H_ + h) * D_ * T_ + t;
#pragma unroll
        for (int d = 0; d < D_; d++) vb[(size_t)d * T_] = (_Float16)acc[d];
    } else {
        _Float16 ob[16];
#pragma unroll
        for (int i = 0; i < D_; i++) ob[i] = (_Float16)(acc[i] * sc);
        _Float16* o = (y == 0) ? Qh : Kh;
        uint4* dst = reinterpret_cast<uint4*>(o + (size_t)((n * H_ + h) * T_ + t) * D_);
        dst[0] = reinterpret_cast<uint4*>(ob)[0];
        dst[1] = reinterpret_cast<uint4*>(ob)[1];
    }
}

// ---------------------------------------------------------------------------
// K2: single-pass fused stats+attn+FC, v5b.
//   Main loop IDENTICAL to R6 (verified): 16 waves x 8 q-tiles, 32 chunks of
//   16 k, exp2 once, ping-pong pA/pB, padded Qs (conflict-free), ds_swizzle
//   XOR-butterfly reduce (R7's DPP row_shr variant was WRONG: sum lands in
//   row 15, not row 0 — reverted), l triple-buffered.
//   NEW: FC fused into the epilogue.  Each (nh,z) block holds the O-partial
//   for all 2048 q x e_in slice [h*16, h*16+16); one 16x16x16 MFMA per
//   (q-tile, e_out-group) against Wt, then atomicAdd into out (16
//   contributors/element: 4 h x 4 z; bias folded as bfc/16).  O is lane-
//   transposed first via per-wave LDS [d][q] — REUSING this wave's Qs region
//   (dead after the last S_PHASE; per-wave private; lgkmcnt(0)+sched_barrier
//   separate the writes from the reads).  Deletes fc_kernel + 33 MB PO write
//   + 33 MB read + one launch; atomic count == old PO store count.
//   REGISTER BUDGET: 64 arch VGPR at waves_per_eu(4,4) (R4/R5/R6 evidence).
//   Spill tell: WRITE_SIZE >> 12 MB.
// ---------------------------------------------------------------------------
#define S_PHASE(PD) do {                                                      \
    lp = (f4){0.f, 0.f, 0.f, 0.f};                                            \
    _Pragma("unroll")                                                         \
    for (int j = 0; j < 8; j++) {                                             \
        h4 bj = *reinterpret_cast<const h4*>(QsW + (j * 16 + row) * 20 + quad * 4); \
        f4 s = __builtin_amdgcn_mfma_f32_16x16x16f16(a, bj, z4, 0, 0, 0);     \
        float e0 = fast_exp2(s[0]), e1 = fast_exp2(s[1]);                     \
        float e2 = fast_exp2(s[2]), e3 = fast_exp2(s[3]);                     \
        lp[0] += e0; lp[1] += e1; lp[2] += e2; lp[3] += e3;                   \
        PD[j] = pack4_f16(e0, e1, e2, e3);                                    \
    }                                                                         \
} while (0)

#define SWZ_STEP(M)                                                           \
    lp[0] += __int_as_float(__builtin_amdgcn_ds_swizzle(__float_as_int(lp[0]), M)); \
    lp[1] += __int_as_float(__builtin_amdgcn_ds_swizzle(__float_as_int(lp[1]), M)); \
    lp[2] += __int_as_float(__builtin_amdgcn_ds_swizzle(__float_as_int(lp[2]), M)); \
    lp[3] += __int_as_float(__builtin_amdgcn_ds_swizzle(__float_as_int(lp[3]), M));

#define REDUCE(BDST) do {                                                     \
    SWZ_STEP(0x041F) SWZ_STEP(0x081F) SWZ_STEP(0x101F) SWZ_STEP(0x201F)       \
    if (row == 0) {                                                           \
        _Pragma("unroll")                                                     \
        for (int i = 0; i < 4; i++) atomicAdd(&l[BDST][quad * 4 + i], lp[i]); \
    }                                                                         \
} while (0)

// iter C: S(C)->PS, reduce(C)->l[b0], PV(C-1) from PPV with l[bm1], zero l[bp1]
#define ITER(C, PS, PPV, KN) do {                                             \
    int k0 = k_lo + (C) * 16;                                                 \
    h4 v = *reinterpret_cast<const h4*>(Vb + (k0 - 16) + quad * 4);           \
    f4 la = *reinterpret_cast<f4*>(&l[bm1][quad * 4]);                        \
    S_PHASE(PS);                                                              \
    h4 na = *reinterpret_cast<const h4*>(Kb + ((KN) + row) * D_ + quad * 4);  \
    REDUCE(b0);                                                               \
    {                                                                         \
        union { g2 g[2]; h4 h; } u_;                                          \
        u_.g[0] = __builtin_amdgcn_cvt_pkrtz(fast_rcp(la[0]), fast_rcp(la[1])); \
        u_.g[1] = __builtin_amdgcn_cvt_pkrtz(fast_rcp(la[2]), fast_rcp(la[3])); \
        v = v * u_.h;                                                         \
    }                                                                         \
    _Pragma("unroll")                                                         \
    for (int j = 0; j < 8; j++)                                               \
        o[j] = __builtin_amdgcn_mfma_f32_16x16x16f16(PPV[j], v, o[j], 0, 0, 0); \
    if (wave == 0 && lane < 16) l[bp1][lane] = 0.f;                           \
    __syncthreads();                                                          \
    a = na;                                                                   \
} while (0)

#define ROT() do { int t_ = bm1; bm1 = b0; b0 = bp1; bp1 = t_; } while (0)

__global__ __attribute__((amdgpu_flat_work_group_size(1024, 1024)))
           __attribute__((amdgpu_waves_per_eu(4, 4)))
void fused_attn_kernel(
    const _Float16* __restrict__ Qh, const _Float16* __restrict__ Kh,
    const _Float16* __restrict__ Vt, const _Float16* __restrict__ Wt,
    const float* __restrict__ bfc, float* __restrict__ out)
{
    __shared__ __align__(16) _Float16 Qs[16 * 128 * 20];   // 80 KB, stride 20
    __shared__ __align__(16) float l[3][16];
    int tid = threadIdx.x;
    int lane = tid & 63, wave = tid >> 6;          // wave 0..15
    int row = lane & 15, quad = lane >> 4;
    int nh = blockIdx.x;
    int z = blockIdx.y;
    int k_lo = z * (T_ / 4);

    const _Float16* Kb = Kh + (size_t)nh * T_ * D_;
    const _Float16* Qb = Qh + (size_t)nh * T_ * D_;
    const _Float16* Vb = Vt + (size_t)nh * D_ * T_ + (size_t)row * T_;

    if (tid < 48) ((float*)l)[tid] = 0.f;

    // stage ALL Q rows for this block (16 waves x 128 rows x 16 halfs) into
    // padded LDS.  Global source is exactly linear in u; LDS dst uint2 index
    // = rr*5 + slot  (20-half row stride).
    {
        const uint2* src = reinterpret_cast<const uint2*>(Qb);
        uint2* dq = reinterpret_cast<uint2*>(Qs);
#pragma unroll
        for (int s = 0; s < 8; s++) {
            int u = s * 1024 + tid;
            dq[(u >> 2) * 5 + (u & 3)] = src[u];
        }
    }
    const _Float16* QsW = Qs + wave * (128 * 20);

    f4 o[8];
#pragma unroll
    for (int j = 0; j < 8; j++) o[j] = (f4){0.f, 0.f, 0.f, 0.f};
    f4 z4 = {0.f, 0.f, 0.f, 0.f};

    h4 a = *reinterpret_cast<const h4*>(Kb + (k_lo + row) * D_ + quad * 4);
    h4 pA[8], pB[8];
    f4 lp;

    __syncthreads();   // l zero-init + Qs staging visible

    // ---- chunk 0 prologue: S -> pA, reduce -> buf 0 (no PV yet)
    S_PHASE(pA);
    {
        h4 na = *reinterpret_cast<const h4*>(Kb + (k_lo + 16 + row) * D_ + quad * 4);
        REDUCE(0);
        __syncthreads();
        a = na;
    }

    int bm1 = 0, b0 = 1, bp1 = 2;
#pragma unroll 1
    for (int c = 1; c < 31; c += 2) {
        ITER(c,     pB, pA, k_lo + c * 16 + 16);
        ROT();
        ITER(c + 1, pA, pB, k_lo + c * 16 + 32);
        ROT();
    }
    ITER(31, pB, pA, k_lo);   // K prefetch wraps (harmless)
    ROT();

    // ---- final PV(31) from pB
    {
        h4 v = *reinterpret_cast<const h4*>(Vb + (k_lo + 31 * 16) + quad * 4);
        f4 la = *reinterpret_cast<f4*>(&l[bm1][quad * 4]);
        union { g2 g[2]; h4 h; } u_;
        u_.g[0] = __builtin_amdgcn_cvt_pkrtz(fast_rcp(la[0]), fast_rcp(la[1]));
        u_.g[1] = __builtin_amdgcn_cvt_pkrtz(fast_rcp(la[2]), fast_rcp(la[3]));
        v = v * u_.h;
#pragma unroll
        for (int j = 0; j < 8; j++)
            o[j] = __builtin_amdgcn_mfma_f32_16x16x16f16(pB[j], v, o[j], 0, 0, 0);
    }

    // ---- fused FC epilogue --------------------------------------------------
    // o[j][i] = O[q = tile+quad*4+i][d = row] (q on regs).  MFMA-A wants q on
    // lanes -> transpose via per-wave LDS written [d][q] (h4 contiguous in q).
    // Qs region of THIS wave is dead (last S_PHASE read long consumed) -> reuse.
    _Float16* Tw = Qs + wave * (128 * 20);     // need 2048 halfs, have 2560
#pragma unroll
    for (int j = 0; j < 8; j++)
        *reinterpret_cast<h4*>(Tw + j * 256 + row * 16 + quad * 4) =
            pack4_f16(o[j][0], o[j][1], o[j][2], o[j][3]);
    asm volatile("s_waitcnt lgkmcnt(0)" ::: "memory");
    __builtin_amdgcn_sched_barrier(0);

    int n = nh >> 2, h = nh & 3;
    // B-frag: lane(row,quad)[i] = W[e_in = h*16+quad*4+i][e_out = ne*16+row]
    //       = Wt[(ne*16+row)*64 + h*16 + quad*4 + i]   (Wt[e][k] = Wfc[k][e])
    h4 wf[4];
    float bb[4];
#pragma unroll
    for (int ne = 0; ne < 4; ne++) {
        wf[ne] = *reinterpret_cast<const h4*>(
            Wt + (size_t)(ne * 16 + row) * 64 + h * 16 + quad * 4);
        bb[ne] = bfc[ne * 16 + row] * 0.0625f;   // 16 contributors -> bfc total
    }
    float* ob = out + (size_t)n * T_ * E_;
#pragma unroll
    for (int j = 0; j < 8; j++) {
        // A-frag: lane(row,quad)[i] = O[q=row][d=quad*4+i] = Tw[j][d][q=row]
        _Float16 r0 = Tw[j * 256 + (quad * 4 + 0) * 16 + row];
        _Float16 r1 = Tw[j * 256 + (quad * 4 + 1) * 16 + row];
        _Float16 r2 = Tw[j * 256 + (quad * 4 + 2) * 16 + row];
        _Float16 r3 = Tw[j * 256 + (quad * 4 + 3) * 16 + row];
        h4 af = (h4){r0, r1, r2, r3};
        int q0 = (wave * 8 + j) * 16;
#pragma unroll
        for (int ne = 0; ne < 4; ne++) {
            f4 acc = __builtin_amdgcn_mfma_f32_16x16x16f16(af, wf[ne], z4, 0, 0, 0);
#pragma unroll
            for (int ii = 0; ii < 4; ii++)
                atomicAdd(ob + (size_t)(q0 + quad * 4 + ii) * E_ + ne * 16 + row,
                          acc[ii] + bb[ne]);
        }
    }
}

extern "C" void kernel_launch(void* const* d_in, const int* in_sizes, int n_in,
                              void* d_out, int out_size, void* d_ws, size_t ws_size,
                              hipStream_t stream) {
    (void)in_sizes; (void)n_in; (void)out_size; (void)ws_size;
    const float* value = (const float*)d_in[0];
    const float* key   = (const float*)d_in[1];
    const float* query = (const float*)d_in[2];
    const float* Wq    = (const float*)d_in[3];
    const float* bq    = (const float*)d_in[4];
    const float* Wk    = (const float*)d_in[5];
    const float* bk    = (const float*)d_in[6];
    const float* Wv    = (const float*)d_in[7];
    const float* bv    = (const float*)d_in[8];
    const float* Wfc   = (const float*)d_in[9];
    const float* bfc   = (const float*)d_in[10];
    float* out = (float*)d_out;

    // ws bytes: Qh 0-4M | Kh 4-8M | Vt 8-12M | Wt 12M
    char* ws = (char*)d_ws;
    _Float16* Qh  = (_Float16*)(ws);
    _Float16* Kh  = (_Float16*)(ws + (4u << 20));
    _Float16* Vt  = (_Float16*)(ws + (8u << 20));
    _Float16* Wt  = (_Float16*)(ws + (12u << 20));

    // proj also zeroes `out` (y==4 slice); same-stream ordering guarantees the
    // zero completes before fused_attn's atomics.
    proj_kernel<<<dim3(512, 5), 256, 0, stream>>>(
        query, Wq, bq, key, Wk, bk, value, Wv, bv, Wfc, Qh, Kh, Vt, Wt, out);
    fused_attn_kernel<<<dim3(NH_, 4), 1024, 0, stream>>>(Qh, Kh, Vt, Wt, bfc, out);
}

// Round 9
// 159.652 us; speedup vs baseline: 1.5708x; 1.5708x over previous
//
#include <hip/hip_runtime.h>

// Problem constants: B=1, N=16, T=2048, E=64, H=4, D=16
#define N_ 16
#define T_ 2048
#define E_ 64
#define H_ 4
#define D_ 16
#define NH_ 64            // N_*H_
#define SEXP_ 0.18033688f // 0.125 * log2(e):  exp(s/8) == exp2(s*SEXP_)

typedef __attribute__((ext_vector_type(4))) _Float16 h4;
typedef __attribute__((ext_vector_type(8))) _Float16 h8;
typedef __attribute__((ext_vector_type(2))) __fp16 g2;
typedef __attribute__((ext_vector_type(4))) float f4;

#if __has_builtin(__builtin_amdgcn_exp2f)
__device__ inline float fast_exp2(float x) { return __builtin_amdgcn_exp2f(x); }
#else
__device__ inline float fast_exp2(float x) {
    float r; asm("v_exp_f32 %0, %1" : "=v"(r) : "v"(x)); return r;
}
#endif

#if __has_builtin(__builtin_amdgcn_rcpf)
__device__ inline float fast_rcp(float x) { return __builtin_amdgcn_rcpf(x); }
#else
__device__ inline float fast_rcp(float x) {
    float r; asm("v_rcp_f32 %0, %1" : "=v"(r) : "v"(x)); return r;
}
#endif

__device__ inline h4 pack4_f16(float a, float b, float c, float d) {
    union { g2 g[2]; h4 h; } u;
    u.g[0] = __builtin_amdgcn_cvt_pkrtz(a, b);
    u.g[1] = __builtin_amdgcn_cvt_pkrtz(c, d);
    return u.h;
}

// ---------------------------------------------------------------------------
// K1: fused projections (y=0 Q pre-scaled, y=1 K, y=2 V-transposed, y=3 Wfc^T)
// ---------------------------------------------------------------------------
__global__ __launch_bounds__(256) void proj_kernel(
    const float* __restrict__ xq, const float* __restrict__ Wq, const float* __restrict__ bq,
    const float* __restrict__ xk, const float* __restrict__ Wk, const float* __restrict__ bk,
    const float* __restrict__ xv, const float* __restrict__ Wv, const float* __restrict__ bv,
    const float* __restrict__ Wfc,
    _Float16* __restrict__ Qh, _Float16* __restrict__ Kh, _Float16* __restrict__ Vt,
    _Float16* __restrict__ Wt)
{
    int tid = threadIdx.x;
    int y = blockIdx.y;
    if (y == 3) {
        if (blockIdx.x < 16) {
            int k = blockIdx.x * 4 + (tid >> 6);
            int e = tid & 63;
            Wt[e * 64 + k] = (_Float16)Wfc[k * 64 + e];
        }
        return;
    }
    const float* x = (y == 0) ? xq : (y == 1) ? xk : xv;
    const float* W = (y == 0) ? Wq : (y == 1) ? Wk : Wv;
    const float* b = (y == 0) ? bq : (y == 1) ? bk : bv;
    const float sc = (y == 0) ? SEXP_ : 1.0f;

    __shared__ float Wl[D_ * D_];
    __shared__ float bl[D_];
    Wl[tid] = W[tid];
    if (tid < D_) bl[tid] = b[tid];
    __syncthreads();

    int r = blockIdx.x * 256 + tid;
    int h, t, n;
    if (y == 2) {          // t fastest: coalesced transposed stores
        t = r & (T_ - 1);
        h = (r >> 11) & (H_ - 1);
        n = r >> 13;
    } else {               // h fastest: coalesced reads
        h = r & (H_ - 1);
        t = (r >> 2) & (T_ - 1);
        n = r >> 13;
    }

    const float4* xp4 = reinterpret_cast<const float4*>(
        x + ((size_t)(n * T_ + t) * E_ + h * D_));
    float xv_[D_];
#pragma unroll
    for (int i = 0; i < 4; i++) {
        float4 v = xp4[i];
        xv_[4*i] = v.x; xv_[4*i+1] = v.y; xv_[4*i+2] = v.z; xv_[4*i+3] = v.w;
    }
    float acc[D_];
#pragma unroll
    for (int i = 0; i < D_; i++) acc[i] = bl[i];
#pragma unroll
    for (int j = 0; j < D_; j++) {
        float xj = xv_[j];
#pragma unroll
        for (int i = 0; i < D_; i++) acc[i] = fmaf(xj, Wl[j * D_ + i], acc[i]);
    }
    if (y == 2) {
        _Float16* vb = Vt + (size_t)(n * H_ + h) * D_ * T_ + t;
#pragma unroll
        for (int d = 0; d < D_; d++) vb[(size_t)d * T_] = (_Float16)acc[d];
    } else {
        _Float16 ob[16];
#pragma unroll
        for (int i = 0; i < D_; i++) ob[i] = (_Float16)(acc[i] * sc);
        _Float16* o = (y == 0) ? Qh : Kh;
        uint4* dst = reinterpret_cast<uint4*>(o + (size_t)((n * H_ + h) * T_ + t) * D_);
        dst[0] = reinterpret_cast<uint4*>(ob)[0];
        dst[1] = reinterpret_cast<uint4*>(ob)[1];
    }
}

// ---------------------------------------------------------------------------
// K2: single-pass fused stats+attn, v6 (R6 structure + barrier-skew hiding).
//   R8 LESSON (refuted FC-fusion): global atomicAdd across XCDs bypasses the
//   non-coherent per-XCD L2 -> 4B of HBM traffic per atomic (WRITE_SIZE 137MB,
//   attn 170us).  Reverted to the verified R6 3-kernel structure.
//   NEW vs R6 (pure code motion, zero register delta):
//   (a) la -> rcp -> V-scale chain hoisted to iteration top: independent of
//       S(c), its ~200cy latency hides under S_PHASE.
//   (b) PV MFMA cluster moved AFTER the barrier: the barrier now waits only
//       on the reduce/atomic tail (not reduce+rcp+PV), and each wave exits
//       into 8 guaranteed-independent MFMAs that overlap the other waves'
//       next S-phase -> converts barrier skew into overlap.  (1 block/CU:
//       nothing else hides the 32 per-chunk barriers.)
//   Buffer safety: zero(bp1) pre-barrier — bp1's last reader (la of iter c-1)
//   is separated by iter c-1's barrier; bp1's next writers (atomics, iter
//   c+1) are beyond this iter's barrier.  PV post-barrier touches only regs.
//   REGISTER BUDGET: 64 arch VGPR at waves_per_eu(4,4) (R4/R5/R6 evidence).
//   Spill tell: WRITE_SIZE >> 34.8 MB.
// ---------------------------------------------------------------------------
#define S_PHASE(PD) do {                                                      \
    lp = (f4){0.f, 0.f, 0.f, 0.f};                                            \
    _Pragma("unroll")                                                         \
    for (int j = 0; j < 8; j++) {                                             \
        h4 bj = *reinterpret_cast<const h4*>(QsW + (j * 16 + row) * 20 + quad * 4); \
        f4 s = __builtin_amdgcn_mfma_f32_16x16x16f16(a, bj, z4, 0, 0, 0);     \
        float e0 = fast_exp2(s[0]), e1 = fast_exp2(s[1]);                     \
        float e2 = fast_exp2(s[2]), e3 = fast_exp2(s[3]);                     \
        lp[0] += e0; lp[1] += e1; lp[2] += e2; lp[3] += e3;                   \
        PD[j] = pack4_f16(e0, e1, e2, e3);                                    \
    }                                                                         \
} while (0)

#define SWZ_STEP(M)                                                           \
    lp[0] += __int_as_float(__builtin_amdgcn_ds_swizzle(__float_as_int(lp[0]), M)); \
    lp[1] += __int_as_float(__builtin_amdgcn_ds_swizzle(__float_as_int(lp[1]), M)); \
    lp[2] += __int_as_float(__builtin_amdgcn_ds_swizzle(__float_as_int(lp[2]), M)); \
    lp[3] += __int_as_float(__builtin_amdgcn_ds_swizzle(__float_as_int(lp[3]), M));

#define REDUCE(BDST) do {                                                     \
    SWZ_STEP(0x041F) SWZ_STEP(0x081F) SWZ_STEP(0x101F) SWZ_STEP(0x201F)       \
    if (row == 0) {                                                           \
        _Pragma("unroll")                                                     \
        for (int i = 0; i < 4; i++) atomicAdd(&l[BDST][quad * 4 + i], lp[i]); \
    }                                                                         \
} while (0)

// iter C: scale(c-1) early; S(C)->PS; reduce(C)->l[b0]; zero l[bp1]; barrier;
//         PV(C-1) from PPV post-barrier.
#define ITER(C, PS, PPV, KN) do {                                             \
    int k0 = k_lo + (C) * 16;                                                 \
    h4 v = *reinterpret_cast<const h4*>(Vb + (k0 - 16) + quad * 4);           \
    f4 la = *reinterpret_cast<f4*>(&l[bm1][quad * 4]);                        \
    h4 vs;                                                                    \
    {                                                                         \
        union { g2 g[2]; h4 h; } u_;                                          \
        u_.g[0] = __builtin_amdgcn_cvt_pkrtz(fast_rcp(la[0]), fast_rcp(la[1])); \
        u_.g[1] = __builtin_amdgcn_cvt_pkrtz(fast_rcp(la[2]), fast_rcp(la[3])); \
        vs = v * u_.h;                                                        \
    }                                                                         \
    S_PHASE(PS);                                                              \
    h4 na = *reinterpret_cast<const h4*>(Kb + ((KN) + row) * D_ + quad * 4);  \
    REDUCE(b0);                                                               \
    if (wave == 0 && lane < 16) l[bp1][lane] = 0.f;                           \
    __syncthreads();                                                          \
    _Pragma("unroll")                                                         \
    for (int j = 0; j < 8; j++)                                               \
        o[j] = __builtin_amdgcn_mfma_f32_16x16x16f16(PPV[j], vs, o[j], 0, 0, 0); \
    a = na;                                                                   \
} while (0)

#define ROT() do { int t_ = bm1; bm1 = b0; b0 = bp1; bp1 = t_; } while (0)

__global__ __attribute__((amdgpu_flat_work_group_size(1024, 1024)))
           __attribute__((amdgpu_waves_per_eu(4, 4)))
void fused_attn_kernel(
    const _Float16* __restrict__ Qh, const _Float16* __restrict__ Kh,
    const _Float16* __restrict__ Vt, float* __restrict__ PO)
{
    __shared__ __align__(16) _Float16 Qs[16 * 128 * 20];   // 80 KB, stride 20
    __shared__ __align__(16) float l[3][16];
    int tid = threadIdx.x;
    int lane = tid & 63, wave = tid >> 6;          // wave 0..15
    int row = lane & 15, quad = lane >> 4;
    int nh = blockIdx.x;
    int z = blockIdx.y;
    int k_lo = z * (T_ / 4);

    const _Float16* Kb = Kh + (size_t)nh * T_ * D_;
    const _Float16* Qb = Qh + (size_t)nh * T_ * D_;
    const _Float16* Vb = Vt + (size_t)nh * D_ * T_ + (size_t)row * T_;

    if (tid < 48) ((float*)l)[tid] = 0.f;

    // stage ALL Q rows for this block (16 waves x 128 rows x 16 halfs) into
    // padded LDS.  Global source is exactly linear in u; LDS dst uint2 index
    // = rr*5 + slot  (20-half row stride).
    {
        const uint2* src = reinterpret_cast<const uint2*>(Qb);
        uint2* dq = reinterpret_cast<uint2*>(Qs);
#pragma unroll
        for (int s = 0; s < 8; s++) {
            int u = s * 1024 + tid;
            dq[(u >> 2) * 5 + (u & 3)] = src[u];
        }
    }
    const _Float16* QsW = Qs + wave * (128 * 20);

    f4 o[8];
#pragma unroll
    for (int j = 0; j < 8; j++) o[j] = (f4){0.f, 0.f, 0.f, 0.f};
    f4 z4 = {0.f, 0.f, 0.f, 0.f};

    h4 a = *reinterpret_cast<const h4*>(Kb + (k_lo + row) * D_ + quad * 4);
    h4 pA[8], pB[8];
    f4 lp;

    __syncthreads();   // l zero-init + Qs staging visible

    // ---- chunk 0 prologue: S -> pA, reduce -> buf 0 (no PV yet)
    S_PHASE(pA);
    {
        h4 na = *reinterpret_cast<const h4*>(Kb + (k_lo + 16 + row) * D_ + quad * 4);
        REDUCE(0);
        __syncthreads();
        a = na;
    }

    int bm1 = 0, b0 = 1, bp1 = 2;
#pragma unroll 1
    for (int c = 1; c < 31; c += 2) {
        ITER(c,     pB, pA, k_lo + c * 16 + 16);
        ROT();
        ITER(c + 1, pA, pB, k_lo + c * 16 + 32);
        ROT();
    }
    ITER(31, pB, pA, k_lo);   // K prefetch wraps (harmless)
    ROT();

    // ---- final PV(31) from pB
    {
        h4 v = *reinterpret_cast<const h4*>(Vb + (k_lo + 31 * 16) + quad * 4);
        f4 la = *reinterpret_cast<f4*>(&l[bm1][quad * 4]);
        union { g2 g[2]; h4 h; } u_;
        u_.g[0] = __builtin_amdgcn_cvt_pkrtz(fast_rcp(la[0]), fast_rcp(la[1]));
        u_.g[1] = __builtin_amdgcn_cvt_pkrtz(fast_rcp(la[2]), fast_rcp(la[3]));
        v = v * u_.h;
#pragma unroll
        for (int j = 0; j < 8; j++)
            o[j] = __builtin_amdgcn_mfma_f32_16x16x16f16(pB[j], v, o[j], 0, 0, 0);
    }

    int n = nh >> 2, h = nh & 3;
    float* po = PO + (size_t)z * N_ * T_ * E_ + (size_t)n * T_ * E_ + h * D_ + row;
#pragma unroll
    for (int j = 0; j < 8; j++)
#pragma unroll
        for (int i = 0; i < 4; i++) {
            int q0 = (wave * 8 + j) * 16 + quad * 4 + i;
            po[(size_t)q0 * E_] = o[j][i];
        }
}

// ---------------------------------------------------------------------------
// K4: fc — out = (sum_z PO[z]) @ Wfc + bfc via 16x16x32 MFMA on Wt.
//     wave: one 16-row M-tile; 2048 tiles -> 512 blocks.
// ---------------------------------------------------------------------------
__global__ __launch_bounds__(256) void fc_kernel(
    const float* __restrict__ PO, const _Float16* __restrict__ Wt,
    const float* __restrict__ bfc, float* __restrict__ out)
{
    int tid = threadIdx.x;
    int lane = tid & 63, wave = tid >> 6;
    int row = lane & 15, quad = lane >> 4;
    int g = blockIdx.x * 4 + wave;             // M-tile id, 2048 total
    int r0 = g * 16;
    size_t base = (size_t)(r0 + row) * E_;
    const size_t zstride = (size_t)N_ * T_ * E_ / 4;   // f4 units

    h8 a[2];
#pragma unroll
    for (int half = 0; half < 2; half++) {
        f4 u0 = {0.f,0.f,0.f,0.f}, u1 = {0.f,0.f,0.f,0.f};
#pragma unroll
        for (int zz = 0; zz < 4; zz++) {
            const f4* p = reinterpret_cast<const f4*>(PO) + zz * zstride + base / 4;
            f4 w0 = p[half * 8 + quad * 2];
            f4 w1 = p[half * 8 + quad * 2 + 1];
#pragma unroll
            for (int i = 0; i < 4; i++) { u0[i] += w0[i]; u1[i] += w1[i]; }
        }
        union { h4 h[2]; h8 v; } pk;
        pk.h[0] = pack4_f16(u0[0], u0[1], u0[2], u0[3]);
        pk.h[1] = pack4_f16(u1[0], u1[1], u1[2], u1[3]);
        a[half] = pk.v;
    }
    f4 acc[4];
#pragma unroll
    for (int ne = 0; ne < 4; ne++) {
        const _Float16* wtb = Wt + (size_t)(ne * 16 + row) * 64;
        h8 b0 = *reinterpret_cast<const h8*>(wtb + quad * 8);
        h8 b1 = *reinterpret_cast<const h8*>(wtb + 32 + quad * 8);
        acc[ne] = __builtin_amdgcn_mfma_f32_16x16x32_f16(a[0], b0, (f4){0.f,0.f,0.f,0.f}, 0, 0, 0);
        acc[ne] = __builtin_amdgcn_mfma_f32_16x16x32_f16(a[1], b1, acc[ne], 0, 0, 0);
    }
#pragma unroll
    for (int ne = 0; ne < 4; ne++) {
        float bias = bfc[ne * 16 + row];
#pragma unroll
        for (int i = 0; i < 4; i++)
            out[(size_t)(r0 + quad * 4 + i) * E_ + ne * 16 + row] = acc[ne][i] + bias;
    }
}

extern "C" void kernel_launch(void* const* d_in, const int* in_sizes, int n_in,
                              void* d_out, int out_size, void* d_ws, size_t ws_size,
                              hipStream_t stream) {
    (void)in_sizes; (void)n_in; (void)out_size; (void)ws_size;
    const float* value = (const float*)d_in[0];
    const float* key   = (const float*)d_in[1];
    const float* query = (const float*)d_in[2];
    const float* Wq    = (const float*)d_in[3];
    const float* bq    = (const float*)d_in[4];
    const float* Wk    = (const float*)d_in[5];
    const float* bk    = (const float*)d_in[6];
    const float* Wv    = (const float*)d_in[7];
    const float* bv    = (const float*)d_in[8];
    const float* Wfc   = (const float*)d_in[9];
    const float* bfc   = (const float*)d_in[10];
    float* out = (float*)d_out;

    // ws bytes: Qh 0-4M | Kh 4-8M | Vt 8-12M | Wt 12M | (13-15M free) | PO 15-47M
    char* ws = (char*)d_ws;
    _Float16* Qh  = (_Float16*)(ws);
    _Float16* Kh  = (_Float16*)(ws + (4u << 20));
    _Float16* Vt  = (_Float16*)(ws + (8u << 20));
    _Float16* Wt  = (_Float16*)(ws + (12u << 20));
    float*    PO  = (float*)   (ws + (15u << 20));

    proj_kernel<<<dim3(512, 4), 256, 0, stream>>>(
        query, Wq, bq, key, Wk, bk, value, Wv, bv, Wfc, Qh, Kh, Vt, Wt);
    fused_attn_kernel<<<dim3(NH_, 4), 1024, 0, stream>>>(Qh, Kh, Vt, PO);
    fc_kernel<<<512, 256, 0, stream>>>(PO, Wt, bfc, out);
}

// Round 10
// 155.624 us; speedup vs baseline: 1.6115x; 1.0259x over previous
//
#include <hip/hip_runtime.h>

// Problem constants: B=1, N=16, T=2048, E=64, H=4, D=16
#define N_ 16
#define T_ 2048
#define E_ 64
#define H_ 4
#define D_ 16
#define NH_ 64            // N_*H_
#define SEXP_ 0.18033688f // 0.125 * log2(e):  exp(s/8) == exp2(s*SEXP_)

typedef __attribute__((ext_vector_type(4))) _Float16 h4;
typedef __attribute__((ext_vector_type(8))) _Float16 h8;
typedef __attribute__((ext_vector_type(2))) __fp16 g2;
typedef __attribute__((ext_vector_type(4))) float f4;

#if __has_builtin(__builtin_amdgcn_exp2f)
__device__ inline float fast_exp2(float x) { return __builtin_amdgcn_exp2f(x); }
#else
__device__ inline float fast_exp2(float x) {
    float r; asm("v_exp_f32 %0, %1" : "=v"(r) : "v"(x)); return r;
}
#endif

#if __has_builtin(__builtin_amdgcn_rcpf)
__device__ inline float fast_rcp(float x) { return __builtin_amdgcn_rcpf(x); }
#else
__device__ inline float fast_rcp(float x) {
    float r; asm("v_rcp_f32 %0, %1" : "=v"(r) : "v"(x)); return r;
}
#endif

__device__ inline h4 pack4_f16(float a, float b, float c, float d) {
    union { g2 g[2]; h4 h; } u;
    u.g[0] = __builtin_amdgcn_cvt_pkrtz(a, b);
    u.g[1] = __builtin_amdgcn_cvt_pkrtz(c, d);
    return u.h;
}

// ---------------------------------------------------------------------------
// K1: fused projections (y=0 Q pre-scaled, y=1 K, y=2 V-transposed, y=3 Wfc^T)
// ---------------------------------------------------------------------------
__global__ __launch_bounds__(256) void proj_kernel(
    const float* __restrict__ xq, const float* __restrict__ Wq, const float* __restrict__ bq,
    const float* __restrict__ xk, const float* __restrict__ Wk, const float* __restrict__ bk,
    const float* __restrict__ xv, const float* __restrict__ Wv, const float* __restrict__ bv,
    const float* __restrict__ Wfc,
    _Float16* __restrict__ Qh, _Float16* __restrict__ Kh, _Float16* __restrict__ Vt,
    _Float16* __restrict__ Wt)
{
    int tid = threadIdx.x;
    int y = blockIdx.y;
    if (y == 3) {
        if (blockIdx.x < 16) {
            int k = blockIdx.x * 4 + (tid >> 6);
            int e = tid & 63;
            Wt[e * 64 + k] = (_Float16)Wfc[k * 64 + e];
        }
        return;
    }
    const float* x = (y == 0) ? xq : (y == 1) ? xk : xv;
    const float* W = (y == 0) ? Wq : (y == 1) ? Wk : Wv;
    const float* b = (y == 0) ? bq : (y == 1) ? bk : bv;
    const float sc = (y == 0) ? SEXP_ : 1.0f;

    __shared__ float Wl[D_ * D_];
    __shared__ float bl[D_];
    Wl[tid] = W[tid];
    if (tid < D_) bl[tid] = b[tid];
    __syncthreads();

    int r = blockIdx.x * 256 + tid;
    int h, t, n;
    if (y == 2) {          // t fastest: coalesced transposed stores
        t = r & (T_ - 1);
        h = (r >> 11) & (H_ - 1);
        n = r >> 13;
    } else {               // h fastest: coalesced reads
        h = r & (H_ - 1);
        t = (r >> 2) & (T_ - 1);
        n = r >> 13;
    }

    const float4* xp4 = reinterpret_cast<const float4*>(
        x + ((size_t)(n * T_ + t) * E_ + h * D_));
    float xv_[D_];
#pragma unroll
    for (int i = 0; i < 4; i++) {
        float4 v = xp4[i];
        xv_[4*i] = v.x; xv_[4*i+1] = v.y; xv_[4*i+2] = v.z; xv_[4*i+3] = v.w;
    }
    float acc[D_];
#pragma unroll
    for (int i = 0; i < D_; i++) acc[i] = bl[i];
#pragma unroll
    for (int j = 0; j < D_; j++) {
        float xj = xv_[j];
#pragma unroll
        for (int i = 0; i < D_; i++) acc[i] = fmaf(xj, Wl[j * D_ + i], acc[i]);
    }
    if (y == 2) {
        _Float16* vb = Vt + (size_t)(n * H_ + h) * D_ * T_ + t;
#pragma unroll
        for (int d = 0; d < D_; d++) vb[(size_t)d * T_] = (_Float16)acc[d];
    } else {
        _Float16 ob[16];
#pragma unroll
        for (int i = 0; i < D_; i++) ob[i] = (_Float16)(acc[i] * sc);
        _Float16* o = (y == 0) ? Qh : Kh;
        uint4* dst = reinterpret_cast<uint4*>(o + (size_t)((n * H_ + h) * T_ + t) * D_);
        dst[0] = reinterpret_cast<uint4*>(ob)[0];
        dst[1] = reinterpret_cast<uint4*>(ob)[1];
    }
}

// ---------------------------------------------------------------------------
// K2: single-pass fused stats+attn, v7 = R6 base (best attn ordering, 68.4us)
//   + two critical-path cuts:
//   (1) DPP reduce: 4x v_add(row_shr 1/2/4/8) per value on the FULL-RATE VALU
//       pipe replaces 16 ds_swizzle LDS round-trips (issue + 4 dependent
//       ~30cy latencies).  Direction fix vs R7's buggy variant: row_shr
//       accumulates UPWARD — after shr 1/2/4/8 lane i holds sum(orig[i-15..i]),
//       so the row sum lands in ROW 15 (atomic gate row==15, NOT row 0).
//   (2) s_setprio(1) around the PV MFMA cluster (T5: favors MFMA-draining
//       wave while barrier-skewed siblings issue loads/exp2).
//   R9's orderings (rcp hoist, post-barrier PV) measured -2% -> reverted.
//   REGISTER BUDGET: 64 arch VGPR at waves_per_eu(4,4) (R4/R5/R6 evidence).
//   Spill tell: WRITE_SIZE >> 37.9 MB.
// ---------------------------------------------------------------------------
#define S_PHASE(PD) do {                                                      \
    lp = (f4){0.f, 0.f, 0.f, 0.f};                                            \
    _Pragma("unroll")                                                         \
    for (int j = 0; j < 8; j++) {                                             \
        h4 bj = *reinterpret_cast<const h4*>(QsW + (j * 16 + row) * 20 + quad * 4); \
        f4 s = __builtin_amdgcn_mfma_f32_16x16x16f16(a, bj, z4, 0, 0, 0);     \
        float e0 = fast_exp2(s[0]), e1 = fast_exp2(s[1]);                     \
        float e2 = fast_exp2(s[2]), e3 = fast_exp2(s[3]);                     \
        lp[0] += e0; lp[1] += e1; lp[2] += e2; lp[3] += e3;                   \
        PD[j] = pack4_f16(e0, e1, e2, e3);                                    \
    }                                                                         \
} while (0)

// DPP row_shr:N accumulate (old=0, bound_ctrl=true -> OOB lanes add 0).
#define DPP_ADD(X, CTRL) do {                                                 \
    int t_ = __builtin_amdgcn_update_dpp(0, __float_as_int(X), CTRL, 0xF, 0xF, true); \
    X += __int_as_float(t_);                                                  \
} while (0)

// After shr 1,2,4,8: lane i = sum(orig[i-15..i]) within its 16-lane DPP row
// (= quad group, rows 0..15) -> ROW 15 holds the full row sum.
#define REDUCE(BDST) do {                                                     \
    _Pragma("unroll")                                                         \
    for (int i = 0; i < 4; i++) {                                             \
        DPP_ADD(lp[i], 0x111); DPP_ADD(lp[i], 0x112);                         \
        DPP_ADD(lp[i], 0x114); DPP_ADD(lp[i], 0x118);                         \
    }                                                                         \
    if (row == 15) {                                                          \
        _Pragma("unroll")                                                     \
        for (int i = 0; i < 4; i++) atomicAdd(&l[BDST][quad * 4 + i], lp[i]); \
    }                                                                         \
} while (0)

// iter C (R6 ordering): S(C)->PS, reduce(C)->l[b0], rcp+scale, PV(C-1) from
// PPV (setprio-wrapped), zero l[bp1], barrier.
#define ITER(C, PS, PPV, KN) do {                                             \
    int k0 = k_lo + (C) * 16;                                                 \
    h4 v = *reinterpret_cast<const h4*>(Vb + (k0 - 16) + quad * 4);           \
    f4 la = *reinterpret_cast<f4*>(&l[bm1][quad * 4]);                        \
    S_PHASE(PS);                                                              \
    h4 na = *reinterpret_cast<const h4*>(Kb + ((KN) + row) * D_ + quad * 4);  \
    REDUCE(b0);                                                               \
    {                                                                         \
        union { g2 g[2]; h4 h; } u_;                                          \
        u_.g[0] = __builtin_amdgcn_cvt_pkrtz(fast_rcp(la[0]), fast_rcp(la[1])); \
        u_.g[1] = __builtin_amdgcn_cvt_pkrtz(fast_rcp(la[2]), fast_rcp(la[3])); \
        v = v * u_.h;                                                         \
    }                                                                         \
    __builtin_amdgcn_s_setprio(1);                                            \
    _Pragma("unroll")                                                         \
    for (int j = 0; j < 8; j++)                                               \
        o[j] = __builtin_amdgcn_mfma_f32_16x16x16f16(PPV[j], v, o[j], 0, 0, 0); \
    __builtin_amdgcn_s_setprio(0);                                            \
    if (wave == 0 && lane < 16) l[bp1][lane] = 0.f;                           \
    __syncthreads();                                                          \
    a = na;                                                                   \
} while (0)

#define ROT() do { int t_ = bm1; bm1 = b0; b0 = bp1; bp1 = t_; } while (0)

__global__ __attribute__((amdgpu_flat_work_group_size(1024, 1024)))
           __attribute__((amdgpu_waves_per_eu(4, 4)))
void fused_attn_kernel(
    const _Float16* __restrict__ Qh, const _Float16* __restrict__ Kh,
    const _Float16* __restrict__ Vt, float* __restrict__ PO)
{
    __shared__ __align__(16) _Float16 Qs[16 * 128 * 20];   // 80 KB, stride 20
    __shared__ __align__(16) float l[3][16];
    int tid = threadIdx.x;
    int lane = tid & 63, wave = tid >> 6;          // wave 0..15
    int row = lane & 15, quad = lane >> 4;
    int nh = blockIdx.x;
    int z = blockIdx.y;
    int k_lo = z * (T_ / 4);

    const _Float16* Kb = Kh + (size_t)nh * T_ * D_;
    const _Float16* Qb = Qh + (size_t)nh * T_ * D_;
    const _Float16* Vb = Vt + (size_t)nh * D_ * T_ + (size_t)row * T_;

    if (tid < 48) ((float*)l)[tid] = 0.f;

    // stage ALL Q rows for this block (16 waves x 128 rows x 16 halfs) into
    // padded LDS.  Global source is exactly linear in u; LDS dst uint2 index
    // = rr*5 + slot  (20-half row stride).
    {
        const uint2* src = reinterpret_cast<const uint2*>(Qb);
        uint2* dq = reinterpret_cast<uint2*>(Qs);
#pragma unroll
        for (int s = 0; s < 8; s++) {
            int u = s * 1024 + tid;
            dq[(u >> 2) * 5 + (u & 3)] = src[u];
        }
    }
    const _Float16* QsW = Qs + wave * (128 * 20);

    f4 o[8];
#pragma unroll
    for (int j = 0; j < 8; j++) o[j] = (f4){0.f, 0.f, 0.f, 0.f};
    f4 z4 = {0.f, 0.f, 0.f, 0.f};

    h4 a = *reinterpret_cast<const h4*>(Kb + (k_lo + row) * D_ + quad * 4);
    h4 pA[8], pB[8];
    f4 lp;

    __syncthreads();   // l zero-init + Qs staging visible

    // ---- chunk 0 prologue: S -> pA, reduce -> buf 0 (no PV yet)
    S_PHASE(pA);
    {
        h4 na = *reinterpret_cast<const h4*>(Kb + (k_lo + 16 + row) * D_ + quad * 4);
        REDUCE(0);
        __syncthreads();
        a = na;
    }

    int bm1 = 0, b0 = 1, bp1 = 2;
#pragma unroll 1
    for (int c = 1; c < 31; c += 2) {
        ITER(c,     pB, pA, k_lo + c * 16 + 16);
        ROT();
        ITER(c + 1, pA, pB, k_lo + c * 16 + 32);
        ROT();
    }
    ITER(31, pB, pA, k_lo);   // K prefetch wraps (harmless)
    ROT();

    // ---- final PV(31) from pB
    {
        h4 v = *reinterpret_cast<const h4*>(Vb + (k_lo + 31 * 16) + quad * 4);
        f4 la = *reinterpret_cast<f4*>(&l[bm1][quad * 4]);
        union { g2 g[2]; h4 h; } u_;
        u_.g[0] = __builtin_amdgcn_cvt_pkrtz(fast_rcp(la[0]), fast_rcp(la[1]));
        u_.g[1] = __builtin_amdgcn_cvt_pkrtz(fast_rcp(la[2]), fast_rcp(la[3]));
        v = v * u_.h;
#pragma unroll
        for (int j = 0; j < 8; j++)
            o[j] = __builtin_amdgcn_mfma_f32_16x16x16f16(pB[j], v, o[j], 0, 0, 0);
    }

    int n = nh >> 2, h = nh & 3;
    float* po = PO + (size_t)z * N_ * T_ * E_ + (size_t)n * T_ * E_ + h * D_ + row;
#pragma unroll
    for (int j = 0; j < 8; j++)
#pragma unroll
        for (int i = 0; i < 4; i++) {
            int q0 = (wave * 8 + j) * 16 + quad * 4 + i;
            po[(size_t)q0 * E_] = o[j][i];
        }
}

// ---------------------------------------------------------------------------
// K4: fc — out = (sum_z PO[z]) @ Wfc + bfc via 16x16x32 MFMA on Wt.
//     wave: one 16-row M-tile; 2048 tiles -> 512 blocks.
// ---------------------------------------------------------------------------
__global__ __launch_bounds__(256) void fc_kernel(
    const float* __restrict__ PO, const _Float16* __restrict__ Wt,
    const float* __restrict__ bfc, float* __restrict__ out)
{
    int tid = threadIdx.x;
    int lane = tid & 63, wave = tid >> 6;
    int row = lane & 15, quad = lane >> 4;
    int g = blockIdx.x * 4 + wave;             // M-tile id, 2048 total
    int r0 = g * 16;
    size_t base = (size_t)(r0 + row) * E_;
    const size_t zstride = (size_t)N_ * T_ * E_ / 4;   // f4 units

    h8 a[2];
#pragma unroll
    for (int half = 0; half < 2; half++) {
        f4 u0 = {0.f,0.f,0.f,0.f}, u1 = {0.f,0.f,0.f,0.f};
#pragma unroll
        for (int zz = 0; zz < 4; zz++) {
            const f4* p = reinterpret_cast<const f4*>(PO) + zz * zstride + base / 4;
            f4 w0 = p[half * 8 + quad * 2];
            f4 w1 = p[half * 8 + quad * 2 + 1];
#pragma unroll
            for (int i = 0; i < 4; i++) { u0[i] += w0[i]; u1[i] += w1[i]; }
        }
        union { h4 h[2]; h8 v; } pk;
        pk.h[0] = pack4_f16(u0[0], u0[1], u0[2], u0[3]);
        pk.h[1] = pack4_f16(u1[0], u1[1], u1[2], u1[3]);
        a[half] = pk.v;
    }
    f4 acc[4];
#pragma unroll
    for (int ne = 0; ne < 4; ne++) {
        const _Float16* wtb = Wt + (size_t)(ne * 16 + row) * 64;
        h8 b0 = *reinterpret_cast<const h8*>(wtb + quad * 8);
        h8 b1 = *reinterpret_cast<const h8*>(wtb + 32 + quad * 8);
        acc[ne] = __builtin_amdgcn_mfma_f32_16x16x32_f16(a[0], b0, (f4){0.f,0.f,0.f,0.f}, 0, 0, 0);
        acc[ne] = __builtin_amdgcn_mfma_f32_16x16x32_f16(a[1], b1, acc[ne], 0, 0, 0);
    }
#pragma unroll
    for (int ne = 0; ne < 4; ne++) {
        float bias = bfc[ne * 16 + row];
#pragma unroll
        for (int i = 0; i < 4; i++)
            out[(size_t)(r0 + quad * 4 + i) * E_ + ne * 16 + row] = acc[ne][i] + bias;
    }
}

extern "C" void kernel_launch(void* const* d_in, const int* in_sizes, int n_in,
                              void* d_out, int out_size, void* d_ws, size_t ws_size,
                              hipStream_t stream) {
    (void)in_sizes; (void)n_in; (void)out_size; (void)ws_size;
    const float* value = (const float*)d_in[0];
    const float* key   = (const float*)d_in[1];
    const float* query = (const float*)d_in[2];
    const float* Wq    = (const float*)d_in[3];
    const float* bq    = (const float*)d_in[4];
    const float* Wk    = (const float*)d_in[5];
    const float* bk    = (const float*)d_in[6];
    const float* Wv    = (const float*)d_in[7];
    const float* bv    = (const float*)d_in[8];
    const float* Wfc   = (const float*)d_in[9];
    const float* bfc   = (const float*)d_in[10];
    float* out = (float*)d_out;

    // ws bytes: Qh 0-4M | Kh 4-8M | Vt 8-12M | Wt 12M | (13-15M free) | PO 15-47M
    char* ws = (char*)d_ws;
    _Float16* Qh  = (_Float16*)(ws);
    _Float16* Kh  = (_Float16*)(ws + (4u << 20));
    _Float16* Vt  = (_Float16*)(ws + (8u << 20));
    _Float16* Wt  = (_Float16*)(ws + (12u << 20));
    float*    PO  = (float*)   (ws + (15u << 20));

    proj_kernel<<<dim3(512, 4), 256, 0, stream>>>(
        query, Wq, bq, key, Wk, bk, value, Wv, bv, Wfc, Qh, Kh, Vt, Wt);
    fused_attn_kernel<<<dim3(NH_, 4), 1024, 0, stream>>>(Qh, Kh, Vt, PO);
    fc_kernel<<<512, 256, 0, stream>>>(PO, Wt, bfc, out);
}

// Round 11
// 155.543 us; speedup vs baseline: 1.6123x; 1.0005x over previous
//
#include <hip/hip_runtime.h>

// Problem constants: B=1, N=16, T=2048, E=64, H=4, D=16
#define N_ 16
#define T_ 2048
#define E_ 64
#define H_ 4
#define D_ 16
#define NH_ 64            // N_*H_
#define SEXP_ 0.18033688f // 0.125 * log2(e):  exp(s/8) == exp2(s*SEXP_)

typedef __attribute__((ext_vector_type(4))) _Float16 h4;
typedef __attribute__((ext_vector_type(8))) _Float16 h8;
typedef __attribute__((ext_vector_type(2))) __fp16 g2;
typedef __attribute__((ext_vector_type(4))) float f4;

#if __has_builtin(__builtin_amdgcn_exp2f)
__device__ inline float fast_exp2(float x) { return __builtin_amdgcn_exp2f(x); }
#else
__device__ inline float fast_exp2(float x) {
    float r; asm("v_exp_f32 %0, %1" : "=v"(r) : "v"(x)); return r;
}
#endif

#if __has_builtin(__builtin_amdgcn_rcpf)
__device__ inline float fast_rcp(float x) { return __builtin_amdgcn_rcpf(x); }
#else
__device__ inline float fast_rcp(float x) {
    float r; asm("v_rcp_f32 %0, %1" : "=v"(r) : "v"(x)); return r;
}
#endif

__device__ inline h4 pack4_f16(float a, float b, float c, float d) {
    union { g2 g[2]; h4 h; } u;
    u.g[0] = __builtin_amdgcn_cvt_pkrtz(a, b);
    u.g[1] = __builtin_amdgcn_cvt_pkrtz(c, d);
    return u.h;
}

// ---------------------------------------------------------------------------
// K1: fused projections (y=0 Q pre-scaled, y=1 K, y=2 V-transposed, y=3 Wfc^T)
// ---------------------------------------------------------------------------
__global__ __launch_bounds__(256) void proj_kernel(
    const float* __restrict__ xq, const float* __restrict__ Wq, const float* __restrict__ bq,
    const float* __restrict__ xk, const float* __restrict__ Wk, const float* __restrict__ bk,
    const float* __restrict__ xv, const float* __restrict__ Wv, const float* __restrict__ bv,
    const float* __restrict__ Wfc,
    _Float16* __restrict__ Qh, _Float16* __restrict__ Kh, _Float16* __restrict__ Vt,
    _Float16* __restrict__ Wt)
{
    int tid = threadIdx.x;
    int y = blockIdx.y;
    if (y == 3) {
        if (blockIdx.x < 16) {
            int k = blockIdx.x * 4 + (tid >> 6);
            int e = tid & 63;
            Wt[e * 64 + k] = (_Float16)Wfc[k * 64 + e];
        }
        return;
    }
    const float* x = (y == 0) ? xq : (y == 1) ? xk : xv;
    const float* W = (y == 0) ? Wq : (y == 1) ? Wk : Wv;
    const float* b = (y == 0) ? bq : (y == 1) ? bk : bv;
    const float sc = (y == 0) ? SEXP_ : 1.0f;

    __shared__ float Wl[D_ * D_];
    __shared__ float bl[D_];
    Wl[tid] = W[tid];
    if (tid < D_) bl[tid] = b[tid];
    __syncthreads();

    int r = blockIdx.x * 256 + tid;
    int h, t, n;
    if (y == 2) {          // t fastest: coalesced transposed stores
        t = r & (T_ - 1);
        h = (r >> 11) & (H_ - 1);
        n = r >> 13;
    } else {               // h fastest: coalesced reads
        h = r & (H_ - 1);
        t = (r >> 2) & (T_ - 1);
        n = r >> 13;
    }

    const float4* xp4 = reinterpret_cast<const float4*>(
        x + ((size_t)(n * T_ + t) * E_ + h * D_));
    float xv_[D_];
#pragma unroll
    for (int i = 0; i < 4; i++) {
        float4 v = xp4[i];
        xv_[4*i] = v.x; xv_[4*i+1] = v.y; xv_[4*i+2] = v.z; xv_[4*i+3] = v.w;
    }
    float acc[D_];
#pragma unroll
    for (int i = 0; i < D_; i++) acc[i] = bl[i];
#pragma unroll
    for (int j = 0; j < D_; j++) {
        float xj = xv_[j];
#pragma unroll
        for (int i = 0; i < D_; i++) acc[i] = fmaf(xj, Wl[j * D_ + i], acc[i]);
    }
    if (y == 2) {
        _Float16* vb = Vt + (size_t)(n * H_ + h) * D_ * T_ + t;
#pragma unroll
        for (int d = 0; d < D_; d++) vb[(size_t)d * T_] = (_Float16)acc[d];
    } else {
        _Float16 ob[16];
#pragma unroll
        for (int i = 0; i < D_; i++) ob[i] = (_Float16)(acc[i] * sc);
        _Float16* o = (y == 0) ? Qh : Kh;
        uint4* dst = reinterpret_cast<uint4*>(o + (size_t)((n * H_ + h) * T_ + t) * D_);
        dst[0] = reinterpret_cast<uint4*>(ob)[0];
        dst[1] = reinterpret_cast<uint4*>(ob)[1];
    }
}

// ---------------------------------------------------------------------------
// K2: single-pass fused stats+attn, v8 = R10 (verified: 62.9us, DPP reduce +
//   setprio, 64 VGPR no-spill) with ONE change: PO stored as f16.
//   attn is ~90% trans-pipe-bound (R10 fit: v_exp_f32 ~32cyc/wave64 -> floor
//   ~57us at this occupancy, which is locked by o[8]+arch ~92 regs/wave).
//   PO-f16 halves attn's PO write (33.5->16.8 MB) and fc's gather read.
//   Precision: PO partials O(1-10), f16 rel 5e-4, 4-way z-sum + Wfc average
//   -> expected absmax ~4-6e-3 (was 2e-3).  Revert if tolerance fails.
//   REGISTER BUDGET: 64 arch VGPR at waves_per_eu(4,4) (R4-R10 evidence).
//   Spill tell: WRITE_SIZE >> 19 MB.
// ---------------------------------------------------------------------------
#define S_PHASE(PD) do {                                                      \
    lp = (f4){0.f, 0.f, 0.f, 0.f};                                            \
    _Pragma("unroll")                                                         \
    for (int j = 0; j < 8; j++) {                                             \
        h4 bj = *reinterpret_cast<const h4*>(QsW + (j * 16 + row) * 20 + quad * 4); \
        f4 s = __builtin_amdgcn_mfma_f32_16x16x16f16(a, bj, z4, 0, 0, 0);     \
        float e0 = fast_exp2(s[0]), e1 = fast_exp2(s[1]);                     \
        float e2 = fast_exp2(s[2]), e3 = fast_exp2(s[3]);                     \
        lp[0] += e0; lp[1] += e1; lp[2] += e2; lp[3] += e3;                   \
        PD[j] = pack4_f16(e0, e1, e2, e3);                                    \
    }                                                                         \
} while (0)

// DPP row_shr:N accumulate (old=0, bound_ctrl=true -> OOB lanes add 0).
#define DPP_ADD(X, CTRL) do {                                                 \
    int t_ = __builtin_amdgcn_update_dpp(0, __float_as_int(X), CTRL, 0xF, 0xF, true); \
    X += __int_as_float(t_);                                                  \
} while (0)

// After shr 1,2,4,8: lane i = sum(orig[i-15..i]) within its 16-lane DPP row
// (= quad group, rows 0..15) -> ROW 15 holds the full row sum.
#define REDUCE(BDST) do {                                                     \
    _Pragma("unroll")                                                         \
    for (int i = 0; i < 4; i++) {                                             \
        DPP_ADD(lp[i], 0x111); DPP_ADD(lp[i], 0x112);                         \
        DPP_ADD(lp[i], 0x114); DPP_ADD(lp[i], 0x118);                         \
    }                                                                         \
    if (row == 15) {                                                          \
        _Pragma("unroll")                                                     \
        for (int i = 0; i < 4; i++) atomicAdd(&l[BDST][quad * 4 + i], lp[i]); \
    }                                                                         \
} while (0)

// iter C (R6 ordering): S(C)->PS, reduce(C)->l[b0], rcp+scale, PV(C-1) from
// PPV (setprio-wrapped), zero l[bp1], barrier.
#define ITER(C, PS, PPV, KN) do {                                             \
    int k0 = k_lo + (C) * 16;                                                 \
    h4 v = *reinterpret_cast<const h4*>(Vb + (k0 - 16) + quad * 4);           \
    f4 la = *reinterpret_cast<f4*>(&l[bm1][quad * 4]);                        \
    S_PHASE(PS);                                                              \
    h4 na = *reinterpret_cast<const h4*>(Kb + ((KN) + row) * D_ + quad * 4);  \
    REDUCE(b0);                                                               \
    {                                                                         \
        union { g2 g[2]; h4 h; } u_;                                          \
        u_.g[0] = __builtin_amdgcn_cvt_pkrtz(fast_rcp(la[0]), fast_rcp(la[1])); \
        u_.g[1] = __builtin_amdgcn_cvt_pkrtz(fast_rcp(la[2]), fast_rcp(la[3])); \
        v = v * u_.h;                                                         \
    }                                                                         \
    __builtin_amdgcn_s_setprio(1);                                            \
    _Pragma("unroll")                                                         \
    for (int j = 0; j < 8; j++)                                               \
        o[j] = __builtin_amdgcn_mfma_f32_16x16x16f16(PPV[j], v, o[j], 0, 0, 0); \
    __builtin_amdgcn_s_setprio(0);                                            \
    if (wave == 0 && lane < 16) l[bp1][lane] = 0.f;                           \
    __syncthreads();                                                          \
    a = na;                                                                   \
} while (0)

#define ROT() do { int t_ = bm1; bm1 = b0; b0 = bp1; bp1 = t_; } while (0)

__global__ __attribute__((amdgpu_flat_work_group_size(1024, 1024)))
           __attribute__((amdgpu_waves_per_eu(4, 4)))
void fused_attn_kernel(
    const _Float16* __restrict__ Qh, const _Float16* __restrict__ Kh,
    const _Float16* __restrict__ Vt, _Float16* __restrict__ PO)
{
    __shared__ __align__(16) _Float16 Qs[16 * 128 * 20];   // 80 KB, stride 20
    __shared__ __align__(16) float l[3][16];
    int tid = threadIdx.x;
    int lane = tid & 63, wave = tid >> 6;          // wave 0..15
    int row = lane & 15, quad = lane >> 4;
    int nh = blockIdx.x;
    int z = blockIdx.y;
    int k_lo = z * (T_ / 4);

    const _Float16* Kb = Kh + (size_t)nh * T_ * D_;
    const _Float16* Qb = Qh + (size_t)nh * T_ * D_;
    const _Float16* Vb = Vt + (size_t)nh * D_ * T_ + (size_t)row * T_;

    if (tid < 48) ((float*)l)[tid] = 0.f;

    // stage ALL Q rows for this block (16 waves x 128 rows x 16 halfs) into
    // padded LDS.  Global source is exactly linear in u; LDS dst uint2 index
    // = rr*5 + slot  (20-half row stride).
    {
        const uint2* src = reinterpret_cast<const uint2*>(Qb);
        uint2* dq = reinterpret_cast<uint2*>(Qs);
#pragma unroll
        for (int s = 0; s < 8; s++) {
            int u = s * 1024 + tid;
            dq[(u >> 2) * 5 + (u & 3)] = src[u];
        }
    }
    const _Float16* QsW = Qs + wave * (128 * 20);

    f4 o[8];
#pragma unroll
    for (int j = 0; j < 8; j++) o[j] = (f4){0.f, 0.f, 0.f, 0.f};
    f4 z4 = {0.f, 0.f, 0.f, 0.f};

    h4 a = *reinterpret_cast<const h4*>(Kb + (k_lo + row) * D_ + quad * 4);
    h4 pA[8], pB[8];
    f4 lp;

    __syncthreads();   // l zero-init + Qs staging visible

    // ---- chunk 0 prologue: S -> pA, reduce -> buf 0 (no PV yet)
    S_PHASE(pA);
    {
        h4 na = *reinterpret_cast<const h4*>(Kb + (k_lo + 16 + row) * D_ + quad * 4);
        REDUCE(0);
        __syncthreads();
        a = na;
    }

    int bm1 = 0, b0 = 1, bp1 = 2;
#pragma unroll 1
    for (int c = 1; c < 31; c += 2) {
        ITER(c,     pB, pA, k_lo + c * 16 + 16);
        ROT();
        ITER(c + 1, pA, pB, k_lo + c * 16 + 32);
        ROT();
    }
    ITER(31, pB, pA, k_lo);   // K prefetch wraps (harmless)
    ROT();

    // ---- final PV(31) from pB
    {
        h4 v = *reinterpret_cast<const h4*>(Vb + (k_lo + 31 * 16) + quad * 4);
        f4 la = *reinterpret_cast<f4*>(&l[bm1][quad * 4]);
        union { g2 g[2]; h4 h; } u_;
        u_.g[0] = __builtin_amdgcn_cvt_pkrtz(fast_rcp(la[0]), fast_rcp(la[1]));
        u_.g[1] = __builtin_amdgcn_cvt_pkrtz(fast_rcp(la[2]), fast_rcp(la[3]));
        v = v * u_.h;
#pragma unroll
        for (int j = 0; j < 8; j++)
            o[j] = __builtin_amdgcn_mfma_f32_16x16x16f16(pB[j], v, o[j], 0, 0, 0);
    }

    int n = nh >> 2, h = nh & 3;
    _Float16* po = PO + (size_t)z * N_ * T_ * E_ + (size_t)n * T_ * E_ + h * D_ + row;
#pragma unroll
    for (int j = 0; j < 8; j++)
#pragma unroll
        for (int i = 0; i < 4; i++) {
            int q0 = (wave * 8 + j) * 16 + quad * 4 + i;
            po[(size_t)q0 * E_] = (_Float16)o[j][i];
        }
}

// ---------------------------------------------------------------------------
// K4: fc — out = (sum_z PO[z]) @ Wfc + bfc via 16x16x32 MFMA on Wt.
//     PO now f16: one h8 (16B) load per (z, half) replaces two f4 loads;
//     z-sum in f32 after convert (no f16-accumulate precision loss).
//     wave: one 16-row M-tile; 2048 tiles -> 512 blocks.
// ---------------------------------------------------------------------------
__global__ __launch_bounds__(256) void fc_kernel(
    const _Float16* __restrict__ PO, const _Float16* __restrict__ Wt,
    const float* __restrict__ bfc, float* __restrict__ out)
{
    int tid = threadIdx.x;
    int lane = tid & 63, wave = tid >> 6;
    int row = lane & 15, quad = lane >> 4;
    int g = blockIdx.x * 4 + wave;             // M-tile id, 2048 total
    int r0 = g * 16;
    size_t base = (size_t)(r0 + row) * E_;             // halfs
    const size_t zstrideh = (size_t)N_ * T_ * E_;      // halfs per z-slice

    h8 a[2];
#pragma unroll
    for (int half = 0; half < 2; half++) {
        f4 u0 = {0.f,0.f,0.f,0.f}, u1 = {0.f,0.f,0.f,0.f};
#pragma unroll
        for (int zz = 0; zz < 4; zz++) {
            h8 w = *reinterpret_cast<const h8*>(
                PO + zz * zstrideh + base + half * 32 + quad * 8);
#pragma unroll
            for (int i = 0; i < 4; i++) {
                u0[i] += (float)w[i];
                u1[i] += (float)w[i + 4];
            }
        }
        union { h4 h[2]; h8 v; } pk;
        pk.h[0] = pack4_f16(u0[0], u0[1], u0[2], u0[3]);
        pk.h[1] = pack4_f16(u1[0], u1[1], u1[2], u1[3]);
        a[half] = pk.v;
    }
    f4 acc[4];
#pragma unroll
    for (int ne = 0; ne < 4; ne++) {
        const _Float16* wtb = Wt + (size_t)(ne * 16 + row) * 64;
        h8 b0 = *reinterpret_cast<const h8*>(wtb + quad * 8);
        h8 b1 = *reinterpret_cast<const h8*>(wtb + 32 + quad * 8);
        acc[ne] = __builtin_amdgcn_mfma_f32_16x16x32_f16(a[0], b0, (f4){0.f,0.f,0.f,0.f}, 0, 0, 0);
        acc[ne] = __builtin_amdgcn_mfma_f32_16x16x32_f16(a[1], b1, acc[ne], 0, 0, 0);
    }
#pragma unroll
    for (int ne = 0; ne < 4; ne++) {
        float bias = bfc[ne * 16 + row];
#pragma unroll
        for (int i = 0; i < 4; i++)
            out[(size_t)(r0 + quad * 4 + i) * E_ + ne * 16 + row] = acc[ne][i] + bias;
    }
}

extern "C" void kernel_launch(void* const* d_in, const int* in_sizes, int n_in,
                              void* d_out, int out_size, void* d_ws, size_t ws_size,
                              hipStream_t stream) {
    (void)in_sizes; (void)n_in; (void)out_size; (void)ws_size;
    const float* value = (const float*)d_in[0];
    const float* key   = (const float*)d_in[1];
    const float* query = (const float*)d_in[2];
    const float* Wq    = (const float*)d_in[3];
    const float* bq    = (const float*)d_in[4];
    const float* Wk    = (const float*)d_in[5];
    const float* bk    = (const float*)d_in[6];
    const float* Wv    = (const float*)d_in[7];
    const float* bv    = (const float*)d_in[8];
    const float* Wfc   = (const float*)d_in[9];
    const float* bfc   = (const float*)d_in[10];
    float* out = (float*)d_out;

    // ws bytes: Qh 0-4M | Kh 4-8M | Vt 8-12M | Wt 12M | PO 15-32M (f16)
    char* ws = (char*)d_ws;
    _Float16* Qh  = (_Float16*)(ws);
    _Float16* Kh  = (_Float16*)(ws + (4u << 20));
    _Float16* Vt  = (_Float16*)(ws + (8u << 20));
    _Float16* Wt  = (_Float16*)(ws + (12u << 20));
    _Float16* PO  = (_Float16*)(ws + (15u << 20));

    proj_kernel<<<dim3(512, 4), 256, 0, stream>>>(
        query, Wq, bq, key, Wk, bk, value, Wv, bv, Wfc, Qh, Kh, Vt, Wt);
    fused_attn_kernel<<<dim3(NH_, 4), 1024, 0, stream>>>(Qh, Kh, Vt, PO);
    fc_kernel<<<512, 256, 0, stream>>>(PO, Wt, bfc, out);
}